// Round 1
// baseline (248.241 us; speedup 1.0000x reference)
//
#include <hip/hip_runtime.h>
#include <math.h>

#define B_  8
#define E_  1024
#define D_  256
#define H_  16
#define FF_ 1024
#define M_  (B_ * E_)   // 8192 rows

typedef __attribute__((ext_vector_type(8))) short short8;
typedef __attribute__((ext_vector_type(4))) float f32x4;
typedef unsigned short bf16u;

#define GLOAD_LDS16(g, l) __builtin_amdgcn_global_load_lds( \
    (const __attribute__((address_space(1))) void*)(g), \
    (__attribute__((address_space(3))) void*)(l), 16, 0, 0)

__device__ __forceinline__ unsigned short f2bf(float f) {
  union { float f; unsigned u; } c; c.f = f;
  unsigned r = c.u + 0x7fffu + ((c.u >> 16) & 1u);   // RNE
  return (unsigned short)(r >> 16);
}
__device__ __forceinline__ float gelu_exact(float x) {
  return 0.5f * x * (1.0f + erff(x * 0.70710678118654752f));
}

// ---------------------------------------------------------------------------
// bf16 MFMA GEMM (unchanged).
// C[M,N] = A[M,K] @ Wt[N,K]^T + bias (+epilogue)
// EPI: 0 = bf16 out (+bias); 1 = f32 out (+bias+R residual); 2 = bf16 gelu.
// ---------------------------------------------------------------------------
template<int BM, int BN, int EPI>
__global__ __launch_bounds__(256) void mm_k(
    const bf16u* __restrict__ A, const bf16u* __restrict__ Wt,
    const float* __restrict__ bias, const float* __restrict__ R,
    void* __restrict__ Cout, int M, int N, int K)
{
  constexpr int WM = BM / 2, WN = BN / 2;
  constexpr int MT = WM / 16, NT = WN / 16;
  constexpr int PA = BM * 8 / 256, PB = BN * 8 / 256;
  constexpr int LBM = (BM == 128 ? 7 : 6), LBN = (BN == 128 ? 7 : 6);
  __shared__ bf16u As[BM * 64];
  __shared__ bf16u Bs[BN * 64];

  const int t = threadIdx.x;
  const int l15 = t & 15, quad = (t >> 4) & 3;
  const int w = t >> 6, wm = w >> 1, wn = w & 1;
  const int m0 = blockIdx.x * BM, n0 = blockIdx.y * BN;

  f32x4 acc[MT][NT];
  const f32x4 z4 = {0.f, 0.f, 0.f, 0.f};
#pragma unroll
  for (int i = 0; i < MT; ++i)
#pragma unroll
    for (int j = 0; j < NT; ++j) acc[i][j] = z4;

  for (int k0 = 0; k0 < K; k0 += 64) {
    __syncthreads();
#pragma unroll
    for (int p = 0; p < PA; ++p) {
      int g = p * 256 + t;
      int m = g & (BM - 1), c = g >> LBM;
      const bf16u* src = A + (size_t)(m0 + m) * K + k0 + c * 8;
      GLOAD_LDS16(src, As + g * 8);
    }
#pragma unroll
    for (int p = 0; p < PB; ++p) {
      int g = p * 256 + t;
      int n = g & (BN - 1), c = g >> LBN;
      const bf16u* src = Wt + (size_t)(n0 + n) * K + k0 + c * 8;
      GLOAD_LDS16(src, Bs + g * 8);
    }
    __syncthreads();
#pragma unroll
    for (int s = 0; s < 2; ++s) {
      short8 af[MT], bfr[NT];
#pragma unroll
      for (int mt = 0; mt < MT; ++mt)
        af[mt] = *(const short8*)(As + ((s * 4 + quad) * BM + wm * WM + mt * 16 + l15) * 8);
#pragma unroll
      for (int nt = 0; nt < NT; ++nt)
        bfr[nt] = *(const short8*)(Bs + ((s * 4 + quad) * BN + wn * WN + nt * 16 + l15) * 8);
#pragma unroll
      for (int mt = 0; mt < MT; ++mt)
#pragma unroll
        for (int nt = 0; nt < NT; ++nt)
          acc[mt][nt] = __builtin_amdgcn_mfma_f32_16x16x32_bf16(
              af[mt], bfr[nt], acc[mt][nt], 0, 0, 0);
    }
  }

#pragma unroll
  for (int mt = 0; mt < MT; ++mt) {
#pragma unroll
    for (int nt = 0; nt < NT; ++nt) {
      int col = n0 + wn * WN + nt * 16 + l15;
      float bia = bias[col];
#pragma unroll
      for (int r = 0; r < 4; ++r) {
        int row = m0 + wm * WM + mt * 16 + quad * 4 + r;
        size_t idx = (size_t)row * N + col;
        float v = acc[mt][nt][r] + bia;
        if (EPI == 1)      { ((float*)Cout)[idx] = v + R[idx]; }
        else if (EPI == 2) { ((bf16u*)Cout)[idx] = f2bf(gelu_exact(v)); }
        else               { ((bf16u*)Cout)[idx] = f2bf(v); }
      }
    }
  }
}

// ---------------------------------------------------------------------------
// 4x fused 256x256 transpose+convert (z selects which weight).
// ---------------------------------------------------------------------------
__global__ __launch_bounds__(256) void tcvt4_k(
    const float* __restrict__ s0, const float* __restrict__ s1,
    const float* __restrict__ s2, const float* __restrict__ s3,
    bf16u* __restrict__ d0, bf16u* __restrict__ d1,
    bf16u* __restrict__ d2, bf16u* __restrict__ d3)
{
  const int z = blockIdx.z;
  const float* src = (z == 0) ? s0 : (z == 1) ? s1 : (z == 2) ? s2 : s3;
  bf16u* dst = (z == 0) ? d0 : (z == 1) ? d1 : (z == 2) ? d2 : d3;
  __shared__ float tile[32][33];
  const int tx = threadIdx.x & 31, ty = threadIdx.x >> 5;
  const int kb = blockIdx.x * 32, nb = blockIdx.y * 32;
#pragma unroll
  for (int r = 0; r < 4; ++r)
    tile[ty + 8 * r][tx] = src[(size_t)(kb + ty + 8 * r) * 256 + nb + tx];
  __syncthreads();
#pragma unroll
  for (int r = 0; r < 4; ++r)
    dst[(size_t)(nb + ty + 8 * r) * 256 + kb + tx] = f2bf(tile[tx][ty + 8 * r]);
}

// generic transpose+convert for the FF weights
__global__ __launch_bounds__(256) void tcvt_k(const float* __restrict__ src,
    bf16u* __restrict__ dst, int K, int N)
{
  __shared__ float tile[32][33];
  const int tx = threadIdx.x & 31, ty = threadIdx.x >> 5;
  const int kb = blockIdx.x * 32, nb = blockIdx.y * 32;
#pragma unroll
  for (int r = 0; r < 4; ++r)
    tile[ty + 8 * r][tx] = src[(size_t)(kb + ty + 8 * r) * N + nb + tx];
  __syncthreads();
#pragma unroll
  for (int r = 0; r < 4; ++r)
    dst[(size_t)(nb + ty + 8 * r) * K + kb + tx] = f2bf(tile[tx][ty + 8 * r]);
}

// fp32 -> bf16 bulk convert (blocks 0..1023) + struct_bias int32 -> u8 pack
// (blocks 1024..5119; sb values are 0..5 so a plain byte store is lossless).
__global__ __launch_bounds__(256) void cvt_k(const float* __restrict__ X,
    bf16u* __restrict__ Y, const int* __restrict__ sb,
    unsigned char* __restrict__ sbb)
{
  const int bid = blockIdx.x;
  if (bid < 1024) {
    int i = bid * 256 + threadIdx.x;
    float4 a = ((const float4*)X)[i * 2];
    float4 b = ((const float4*)X)[i * 2 + 1];
    uint4 o;
    o.x = f2bf(a.x) | ((unsigned)f2bf(a.y) << 16);
    o.y = f2bf(a.z) | ((unsigned)f2bf(a.w) << 16);
    o.z = f2bf(b.x) | ((unsigned)f2bf(b.y) << 16);
    o.w = f2bf(b.z) | ((unsigned)f2bf(b.w) << 16);
    ((uint4*)Y)[i] = o;
  } else {
    int i = (bid - 1024) * 256 + threadIdx.x;   // 8 ints -> 8 bytes per thread
    int4 a = ((const int4*)sb)[i * 2];
    int4 c = ((const int4*)sb)[i * 2 + 1];
    uint2 o;
    o.x = (unsigned)a.x | ((unsigned)a.y << 8) | ((unsigned)a.z << 16) | ((unsigned)a.w << 24);
    o.y = (unsigned)c.x | ((unsigned)c.y << 8) | ((unsigned)c.z << 16) | ((unsigned)c.w << 24);
    ((uint2*)sbb)[i] = o;
  }
}

// concat bq|bk|bv -> bqkv[768]
__global__ void bcat_k(const float* __restrict__ bq, const float* __restrict__ bk,
                       const float* __restrict__ bv, float* __restrict__ o)
{
  int i = blockIdx.x * 256 + threadIdx.x;
  o[i] = (i < 256) ? bq[i] : (i < 512) ? bk[i - 256] : bv[i - 512];
}

// ---------------------------------------------------------------------------
// MFMA flash attention with structural bias — per-HEAD blocks for occupancy.
// Grid (16 qblocks, 16 heads, 8 batch) = 2048 blocks x 4 waves = 32 waves/CU
// (was 1024 blocks = 50% occupancy cap). Wave w owns q-rows [q0+w*16,+16) of
// its block's single head. Per 32-key group: 2x mfma_16x16x32 QK^T (d padded
// 16->32; dead k=16 slot injects key-padding mask via Q=1.0, K=-4e9*mask),
// p = exp2(fma(s, 0.25*log2e, emb2)) with emb2 pre-scaled by log2e (saves the
// v_mul hidden in __expf), p truncated to bf16, round-tripped through LDS
// (sigma-permuted packed b32 columns), one PV MFMA with V staged transposed
// in the same permutation. Vt padded 72->74: rows j/j+8 were bank-aliased
// (8*36 % 32 == 0) -> 4-way write conflicts; stride 37 words fixes it.
// sb prefetched per chunk as u8 (pre-packed by cvt_k; 4x less L2 traffic).
// ---------------------------------------------------------------------------
__global__ __launch_bounds__(256) void attn_k(
    const bf16u* __restrict__ qkv, const unsigned char* __restrict__ sbb,
    const unsigned char* __restrict__ mask, const float* __restrict__ be,
    bf16u* __restrict__ O)
{
  __shared__ bf16u Kl[64][40];   // [key][d: 0-15 data,16 mask,17-31 zero,pad]
  __shared__ bf16u Vt[16][74];   // [d][sigma-permuted key cols + pad]
  __shared__ bf16u Pl[4][16][40];// per-wave P tile [q][sigma cols + pad]
  __shared__ float embl[6];

  const int t    = threadIdx.x;
  const int b    = blockIdx.z;
  const int h    = blockIdx.y;          // head 0..15
  const int w    = t >> 6;
  const int lane = t & 63;
  const int l15  = lane & 15;
  const int quad = lane >> 4;
  const int q0w  = blockIdx.x * 64 + w * 16;
  const float C2 = 0.36067376022224085f;   // 0.25 * log2(e)

  if (t < 6) embl[t] = be[t * 16 + h] * 1.44269504088896f;

  {  // zero Kl once: cols 17..31 must stay 0 for the padded MFMA
    float4 z = {0.f, 0.f, 0.f, 0.f};
    float4* kp = (float4*)&Kl[0][0];
    for (int i = t; i < 320; i += 256) kp[i] = z;
  }

  // Q A-frag: lane l15=q-row, k=quad*8+j; quads 2,3 are the zero-pad half
  // except k=16 (quad2,j0) = 1.0 for the mask-inject trick.
  short8 qf;
  {
    uint4 v = {0u, 0u, 0u, 0u};
    if (quad < 2)
      v = *(const uint4*)(qkv + ((size_t)(b * E_) + q0w + l15) * 768 +
                          h * 16 + quad * 8);
    else if (quad == 2)
      v.x = 0x3F80u;  // bf16 1.0 in low half (element j=0)
    union { uint4 u; short8 s; } c; c.u = v;
    qf = c.s;
  }

  const int s_key  = (t >> 1) & 63;  // staging: key within chunk
  const int s_half = t & 1;          // staging: d-half
  const size_t kvbase = (size_t)b * E_ * 768;
  const unsigned char* sbp = sbb + ((size_t)(b * E_) + q0w) * E_;

  f32x4 accO;
  const f32x4 z4 = {0.f, 0.f, 0.f, 0.f};
  accO = z4;
  float lsum[4] = {};

  for (int k0 = 0; k0 < E_; k0 += 64) {
    // prefetch sb bytes for this chunk (16 per lane; covered by staging)
    int sbv[2][2][4];
#pragma unroll
    for (int s2 = 0; s2 < 2; ++s2)
#pragma unroll
      for (int f = 0; f < 2; ++f)
#pragma unroll
        for (int r = 0; r < 4; ++r)
          sbv[s2][f][r] = sbp[(size_t)(quad * 4 + r) * E_ + k0 + s2 * 32 + f * 16 + l15];

    __syncthreads();  // previous chunk fully consumed before overwrite
    {
      const bf16u* base = qkv + kvbase + (size_t)(k0 + s_key) * 768 +
                          h * 16 + s_half * 8;
      if (t < 128) {   // waves 0,1: K rows + mask column
        *(uint4*)&Kl[s_key][s_half * 8] = *(const uint4*)(base + 256);
        if (t < 64) {
          unsigned char mv = mask[b * E_ + k0 + t];
          Kl[t][16] = mv ? (bf16u)0xCF6E : (bf16u)0;  // -4e9 : 0
        }
      } else {         // waves 2,3: V transposed into sigma columns
        uint4 vw = *(const uint4*)(base + 512);
        const int col = (s_key >> 5) * 32 + ((s_key & 15) << 1) + ((s_key >> 4) & 1);
        union { uint4 u; bf16u e[8]; } vc; vc.u = vw;
#pragma unroll
        for (int j = 0; j < 8; ++j)
          Vt[s_half * 8 + j][col] = vc.e[j];
      }
    }
    __syncthreads();

#pragma unroll
    for (int s2 = 0; s2 < 2; ++s2) {
      short8 kf0 = *(const short8*)&Kl[s2 * 32 + l15][quad * 8];
      short8 kf1 = *(const short8*)&Kl[s2 * 32 + 16 + l15][quad * 8];
      f32x4 sc0 = __builtin_amdgcn_mfma_f32_16x16x32_bf16(qf, kf0, z4, 0, 0, 0);
      f32x4 sc1 = __builtin_amdgcn_mfma_f32_16x16x32_bf16(qf, kf1, z4, 0, 0, 0);
#pragma unroll
      for (int r = 0; r < 4; ++r) {
        float w0 = embl[sbv[s2][0][r]];
        float w1 = embl[sbv[s2][1][r]];
        float p0 = __builtin_amdgcn_exp2f(fmaf(sc0[r], C2, w0));
        float p1 = __builtin_amdgcn_exp2f(fmaf(sc1[r], C2, w1));
        unsigned u0 = __float_as_uint(p0) & 0xffff0000u;
        unsigned u1 = __float_as_uint(p1) & 0xffff0000u;
        lsum[r] += __uint_as_float(u0) + __uint_as_float(u1);
        // packed pair: col 2*l15 (p0, low) | col 2*l15+1 (p1, high)
        *(unsigned*)&Pl[w][quad * 4 + r][l15 * 2] = (__float_as_uint(p0) >> 16) | u1;
      }
      short8 pf = *(const short8*)&Pl[w][l15][quad * 8];
      short8 vf = *(const short8*)&Vt[l15][s2 * 32 + quad * 8];
      accO = __builtin_amdgcn_mfma_f32_16x16x32_bf16(pf, vf, accO, 0, 0, 0);
    }
  }

  // reduce l over the 16 key-lanes (C-layout rows live in quad, cols in l15)
#pragma unroll
  for (int off = 1; off <= 8; off <<= 1)
#pragma unroll
    for (int r = 0; r < 4; ++r)
      lsum[r] += __shfl_xor(lsum[r], off, 64);

#pragma unroll
  for (int r = 0; r < 4; ++r) {
    float o = accO[r] / lsum[r];
    O[((size_t)(b * E_) + q0w + quad * 4 + r) * 256 + h * 16 + l15] = f2bf(o);
  }
}

// ---------------------------------------------------------------------------
// LayerNorm, one wave per row of 256. DUAL: also write bf16 copy.
// ---------------------------------------------------------------------------
template<int DUAL>
__global__ __launch_bounds__(256) void ln_k(
    const float* __restrict__ X, const float* __restrict__ g,
    const float* __restrict__ bta, float* __restrict__ Y, bf16u* __restrict__ Yb)
{
  const int row  = blockIdx.x * 4 + (threadIdx.x >> 6);
  const int lane = threadIdx.x & 63;
  float4 v = *(const float4*)(X + (size_t)row * D_ + lane * 4);
  float s  = v.x + v.y + v.z + v.w;
  float ss = v.x * v.x + v.y * v.y + v.z * v.z + v.w * v.w;
#pragma unroll
  for (int off = 32; off; off >>= 1) {
    s  += __shfl_xor(s, off, 64);
    ss += __shfl_xor(ss, off, 64);
  }
  float mu  = s * (1.f / 256.f);
  float var = ss * (1.f / 256.f) - mu * mu;
  float rs  = 1.f / sqrtf(var + 1e-5f);
  float4 gv = *(const float4*)(g + lane * 4);
  float4 bv = *(const float4*)(bta + lane * 4);
  float4 o;
  o.x = (v.x - mu) * rs * gv.x + bv.x;
  o.y = (v.y - mu) * rs * gv.y + bv.y;
  o.z = (v.z - mu) * rs * gv.z + bv.z;
  o.w = (v.w - mu) * rs * gv.w + bv.w;
  *(float4*)(Y + (size_t)row * D_ + lane * 4) = o;
  if (DUAL) {
    uint2 p;
    p.x = f2bf(o.x) | ((unsigned)f2bf(o.y) << 16);
    p.y = f2bf(o.z) | ((unsigned)f2bf(o.w) << 16);
    *(uint2*)(Yb + (size_t)row * D_ + lane * 4) = p;
  }
}

// ---------------------------------------------------------------------------
extern "C" void kernel_launch(void* const* d_in, const int* in_sizes, int n_in,
                              void* d_out, int out_size, void* d_ws, size_t ws_size,
                              hipStream_t stream) {
  const float* x   = (const float*)d_in[0];
  const int*   sb  = (const int*)d_in[1];
  const unsigned char* mask = (const unsigned char*)d_in[2];
  const float* Wq  = (const float*)d_in[3];
  const float* bq  = (const float*)d_in[4];
  const float* Wk  = (const float*)d_in[5];
  const float* bk  = (const float*)d_in[6];
  const float* Wv  = (const float*)d_in[7];
  const float* bv  = (const float*)d_in[8];
  const float* Wo  = (const float*)d_in[9];
  const float* bo  = (const float*)d_in[10];
  const float* be  = (const float*)d_in[11];
  const float* g1  = (const float*)d_in[12];
  const float* b1  = (const float*)d_in[13];
  const float* Wf1 = (const float*)d_in[14];
  const float* bf1 = (const float*)d_in[15];
  const float* Wf2 = (const float*)d_in[16];
  const float* bf2 = (const float*)d_in[17];
  const float* g2  = (const float*)d_in[18];
  const float* b2  = (const float*)d_in[19];
  float* out = (float*)d_out;

  // workspace layout (byte offsets); peak ~44 MB
  char* ws = (char*)d_ws;
  bf16u* Wqkvt = (bf16u*)(ws + 0);          // 768*256*2
  bf16u* Wot   = (bf16u*)(ws + 393216);     // 256*256*2
  bf16u* Wf1t  = (bf16u*)(ws + 524288);     // 1024*256*2
  bf16u* Wf2t  = (bf16u*)(ws + 1048576);    // 256*1024*2
  float* bqkv  = (float*)(ws + 1572864);    // 768*4
  bf16u* xb    = (bf16u*)(ws + 2097152);    // 4 MB   [dead after qkv gemm]
  bf16u* qkv   = (bf16u*)(ws + 6291456);    // 12.6 MB [dead after attn]
  bf16u* att   = (bf16u*)(ws + 18874368);   // 4 MB
  unsigned char* sbb = (unsigned char*)(ws + 23068672); // 8.4 MB [dead after attn]
  float* t1    = (float*)(ws + 23068672);   // 8 MB, reuses sbb [dead after ln1]
  float* x1    = (float*)(ws + 31457280);   // 8 MB
  bf16u* x1b   = (bf16u*)(ws + 39845888);   // 4 MB
  bf16u* ffh   = (bf16u*)(ws + 2097152);    // 16 MB, reuses xb+qkv
  float* t2    = (float*)(ws + 18874368);   // 8 MB, reuses att+t1

  dim3 blk(256);

  tcvt4_k<<<dim3(8, 8, 4), blk, 0, stream>>>(Wq, Wk, Wv, Wo,
      Wqkvt, Wqkvt + 65536, Wqkvt + 131072, Wot);
  tcvt_k<<<dim3(8, 32), blk, 0, stream>>>(Wf1, Wf1t, 256, 1024);
  tcvt_k<<<dim3(32, 8), blk, 0, stream>>>(Wf2, Wf2t, 1024, 256);
  bcat_k<<<3, blk, 0, stream>>>(bq, bk, bv, bqkv);
  cvt_k<<<5120, blk, 0, stream>>>(x, xb, sb, sbb);

  // QKV projection (fused, N=768) -> qkv bf16 (64x128 tiles: 768 blocks, 3/CU)
  mm_k<64, 128, 0><<<dim3(128, 6), blk, 0, stream>>>(xb, Wqkvt, bqkv, nullptr,
                                                     qkv, M_, 768, 256);
  // MFMA flash attention -> att bf16 (per-head blocks: 2048, 8/CU, 32 waves)
  attn_k<<<dim3(16, 16, 8), blk, 0, stream>>>(qkv, sbb, mask, be, att);

  // out-proj + residual -> t1 fp32; ln1 -> x1 fp32 + x1b bf16
  mm_k<64, 64, 1><<<dim3(128, 4), blk, 0, stream>>>(att, Wot, bo, x,
                                                    t1, M_, 256, 256);
  ln_k<1><<<M_ / 4, blk, 0, stream>>>(t1, g1, b1, x1, x1b);

  // FFN
  mm_k<128, 128, 2><<<dim3(64, 8), blk, 0, stream>>>(x1b, Wf1t, bf1, nullptr,
                                                     ffh, M_, 1024, 256);
  mm_k<64, 64, 1><<<dim3(128, 4), blk, 0, stream>>>(ffh, Wf2t, bf2, x1,
                                                    t2, M_, 256, 1024);
  ln_k<0><<<M_ / 4, blk, 0, stream>>>(t2, g2, b2, out, nullptr);
}